// Round 1
// baseline (5664.381 us; speedup 1.0000x reference)
//
#include <hip/hip_runtime.h>
#include <math.h>

#define NB 8192
#define S_ 45
#define D_ 64
#define H_ 8
#define HD_ 8
#define FF_ 256

__global__ void pe_kernel(float* __restrict__ pe) {
    int idx = blockIdx.x * 256 + threadIdx.x;
    if (idx < S_ * D_) {
        int s = idx / D_, d = idx % D_;
        float div = expf(-logf(10000.0f) * (float)(d & ~1) / (float)D_);
        float ang = (float)s * div;
        pe[idx] = (d & 1) ? cosf(ang) : sinf(ang);
    }
}

__device__ inline void fma4x4(float4& acc, const float4 hv,
                              const float4 w0, const float4 w1,
                              const float4 w2, const float4 w3) {
    acc.x += hv.x * w0.x + hv.y * w1.x + hv.z * w2.x + hv.w * w3.x;
    acc.y += hv.x * w0.y + hv.y * w1.y + hv.z * w2.y + hv.w * w3.y;
    acc.z += hv.x * w0.z + hv.y * w1.z + hv.z * w2.z + hv.w * w3.z;
    acc.w += hv.x * w0.w + hv.y * w1.w + hv.z * w2.w + hv.w * w3.w;
}

__launch_bounds__(256, 2)
__global__ void encoder_kernel(
    const float* __restrict__ x,
    const float* __restrict__ Wq, const float* __restrict__ bq,
    const float* __restrict__ Wk, const float* __restrict__ bk,
    const float* __restrict__ Wv, const float* __restrict__ bv,
    const float* __restrict__ Wo, const float* __restrict__ bo,
    const float* __restrict__ ln1g, const float* __restrict__ ln1b,
    const float* __restrict__ W1, const float* __restrict__ b1,
    const float* __restrict__ W2, const float* __restrict__ b2,
    const float* __restrict__ ln2g, const float* __restrict__ ln2b,
    const float* __restrict__ pe,
    float* __restrict__ out)
{
    // LDS layout:
    //   h  [45][64]  : h = x+pe, later h2 (post-LN1), later t2 (pre-LN2)
    //   U  [12288]   : q[48][64] | k[48][64] | v[48][64] | o[48][64]
    //                  overlaid by f[45][256] for the FFN
    __shared__ float h[S_ * D_];
    __shared__ float U[12288];
    float* qs = U;
    float* ks = U + 3072;
    float* vs = U + 6144;
    float* os = U + 9216;
    float* fs = U;                   // [45][256] overlay

    const int t = threadIdx.x;
    const int b = blockIdx.x;
    const float* xb = x + (size_t)b * (S_ * D_);

    // ---- 1. h = x + pe -------------------------------------------------
    {
        const float4* x4 = (const float4*)xb;
        const float4* p4 = (const float4*)pe;
        float4* h4 = (float4*)h;
        for (int i = t; i < S_ * D_ / 4; i += 256) {
            float4 a = x4[i], p = p4[i];
            h4[i] = make_float4(a.x + p.x, a.y + p.y, a.z + p.z, a.w + p.w);
        }
    }
    __syncthreads();

    // ---- 2. Q,K,V projections (fused) ---------------------------------
    // thread: col c = t&63, row-group rg = t>>6; rows r = rg + 4i
    {
        const int c = t & 63, rg = t >> 6;
        float aq[12], ak[12], av[12];
        #pragma unroll
        for (int i = 0; i < 12; i++) { aq[i] = 0.f; ak[i] = 0.f; av[i] = 0.f; }
        for (int k4 = 0; k4 < D_; k4 += 4) {
            float4 hv[12];
            #pragma unroll
            for (int i = 0; i < 12; i++) {
                int r = rg + 4 * i;
                hv[i] = (r < S_) ? *(const float4*)&h[r * 64 + k4]
                                 : make_float4(0.f, 0.f, 0.f, 0.f);
            }
            float wq0 = Wq[(k4 + 0) * 64 + c], wq1 = Wq[(k4 + 1) * 64 + c];
            float wq2 = Wq[(k4 + 2) * 64 + c], wq3 = Wq[(k4 + 3) * 64 + c];
            float wk0 = Wk[(k4 + 0) * 64 + c], wk1 = Wk[(k4 + 1) * 64 + c];
            float wk2 = Wk[(k4 + 2) * 64 + c], wk3 = Wk[(k4 + 3) * 64 + c];
            float wv0 = Wv[(k4 + 0) * 64 + c], wv1 = Wv[(k4 + 1) * 64 + c];
            float wv2 = Wv[(k4 + 2) * 64 + c], wv3 = Wv[(k4 + 3) * 64 + c];
            #pragma unroll
            for (int i = 0; i < 12; i++) {
                aq[i] += hv[i].x * wq0 + hv[i].y * wq1 + hv[i].z * wq2 + hv[i].w * wq3;
                ak[i] += hv[i].x * wk0 + hv[i].y * wk1 + hv[i].z * wk2 + hv[i].w * wk3;
                av[i] += hv[i].x * wv0 + hv[i].y * wv1 + hv[i].z * wv2 + hv[i].w * wv3;
            }
        }
        float bqc = bq[c], bkc = bk[c], bvc = bv[c];
        #pragma unroll
        for (int i = 0; i < 12; i++) {
            int r = rg + 4 * i;
            if (r < S_) {
                qs[r * 64 + c] = aq[i] + bqc;
                ks[r * 64 + c] = ak[i] + bkc;
                vs[r * 64 + c] = av[i] + bvc;
            }
        }
    }
    __syncthreads();

    // ---- 3. attention (per head, scores in registers) ------------------
    {
        const float scale = 0.35355339059327373f;  // 1/sqrt(8)
        for (int qr0 = 0; qr0 < S_; qr0 += 32) {
            int qr = qr0 + (t >> 3);
            int hd = (t & 7) * HD_;
            if (qr < S_) {
                float4 qa = *(const float4*)&qs[qr * 64 + hd];
                float4 qb = *(const float4*)&qs[qr * 64 + hd + 4];
                float sc[S_];
                #pragma unroll
                for (int k = 0; k < S_; k++) {
                    float4 ka = *(const float4*)&ks[k * 64 + hd];
                    float4 kb = *(const float4*)&ks[k * 64 + hd + 4];
                    sc[k] = (qa.x * ka.x + qa.y * ka.y + qa.z * ka.z + qa.w * ka.w +
                             qb.x * kb.x + qb.y * kb.y + qb.z * kb.z + qb.w * kb.w) * scale;
                }
                float m = sc[0];
                #pragma unroll
                for (int k = 1; k < S_; k++) m = fmaxf(m, sc[k]);
                float sum = 0.f;
                #pragma unroll
                for (int k = 0; k < S_; k++) { sc[k] = __expf(sc[k] - m); sum += sc[k]; }
                float inv = 1.0f / sum;
                float4 oa = make_float4(0.f, 0.f, 0.f, 0.f);
                float4 ob = make_float4(0.f, 0.f, 0.f, 0.f);
                #pragma unroll
                for (int k = 0; k < S_; k++) {
                    float p = sc[k] * inv;
                    float4 va = *(const float4*)&vs[k * 64 + hd];
                    float4 vb = *(const float4*)&vs[k * 64 + hd + 4];
                    oa.x += p * va.x; oa.y += p * va.y; oa.z += p * va.z; oa.w += p * va.w;
                    ob.x += p * vb.x; ob.y += p * vb.y; ob.z += p * vb.z; ob.w += p * vb.w;
                }
                *(float4*)&os[qr * 64 + hd]     = oa;
                *(float4*)&os[qr * 64 + hd + 4] = ob;
            }
        }
    }
    __syncthreads();

    // ---- 4. o @ Wo + bo + h (residual) -> t1 into q-space --------------
    // thread: cols c0..c0+3 (c0=(t&15)*4), rows r = (t>>4) + 16i
    {
        const int c0 = (t & 15) * 4, rg = t >> 4;
        float4 acc[3];
        #pragma unroll
        for (int i = 0; i < 3; i++) acc[i] = make_float4(0.f, 0.f, 0.f, 0.f);
        for (int k4 = 0; k4 < D_; k4 += 4) {
            float4 ov[3];
            #pragma unroll
            for (int i = 0; i < 3; i++) {
                int r = rg + 16 * i;
                ov[i] = (r < S_) ? *(const float4*)&os[r * 64 + k4]
                                 : make_float4(0.f, 0.f, 0.f, 0.f);
            }
            float4 w0 = *(const float4*)&Wo[(k4 + 0) * 64 + c0];
            float4 w1 = *(const float4*)&Wo[(k4 + 1) * 64 + c0];
            float4 w2 = *(const float4*)&Wo[(k4 + 2) * 64 + c0];
            float4 w3 = *(const float4*)&Wo[(k4 + 3) * 64 + c0];
            #pragma unroll
            for (int i = 0; i < 3; i++) fma4x4(acc[i], ov[i], w0, w1, w2, w3);
        }
        float4 bo4 = *(const float4*)&bo[c0];
        #pragma unroll
        for (int i = 0; i < 3; i++) {
            int r = rg + 16 * i;
            if (r < S_) {
                float4 hr = *(const float4*)&h[r * 64 + c0];
                float4 o;
                o.x = acc[i].x + bo4.x + hr.x;
                o.y = acc[i].y + bo4.y + hr.y;
                o.z = acc[i].z + bo4.z + hr.z;
                o.w = acc[i].w + bo4.w + hr.w;
                *(float4*)&qs[r * 64 + c0] = o;   // t1
            }
        }
    }
    __syncthreads();

    // ---- 5. LN1: t1 (q-space) -> h2 (h-space) --------------------------
    {
        const int wv = t >> 6, d = t & 63;
        const float g = ln1g[d], bb = ln1b[d];
        for (int i = 0; i < 12; i++) {
            int r = wv + 4 * i;
            if (r < S_) {
                float v = qs[r * 64 + d];
                float s = v, s2 = v * v;
                #pragma unroll
                for (int off = 32; off; off >>= 1) {
                    s += __shfl_xor(s, off);
                    s2 += __shfl_xor(s2, off);
                }
                float mean = s * (1.0f / 64.0f);
                float var = s2 * (1.0f / 64.0f) - mean * mean;
                float nv = (v - mean) * rsqrtf(var + 1e-5f);
                h[r * 64 + d] = nv * g + bb;
            }
        }
    }
    __syncthreads();

    // ---- 6. FFN1: f = relu(h2 @ W1 + b1) into U overlay ----------------
    // thread: cols c0..c0+3 (c0=(t&63)*4), row chunks of 16, rows rg*4+i
    {
        const int c0 = (t & 63) * 4, rg = t >> 6;
        float4 bias = *(const float4*)&b1[c0];
        for (int ch = 0; ch < 3; ch++) {
            float4 acc[4];
            #pragma unroll
            for (int i = 0; i < 4; i++) acc[i] = make_float4(0.f, 0.f, 0.f, 0.f);
            for (int k4 = 0; k4 < D_; k4 += 4) {
                float4 hv[4];
                #pragma unroll
                for (int i = 0; i < 4; i++) {
                    int r = ch * 16 + rg * 4 + i;
                    hv[i] = (r < S_) ? *(const float4*)&h[r * 64 + k4]
                                     : make_float4(0.f, 0.f, 0.f, 0.f);
                }
                float4 w0 = *(const float4*)&W1[(k4 + 0) * FF_ + c0];
                float4 w1 = *(const float4*)&W1[(k4 + 1) * FF_ + c0];
                float4 w2 = *(const float4*)&W1[(k4 + 2) * FF_ + c0];
                float4 w3 = *(const float4*)&W1[(k4 + 3) * FF_ + c0];
                #pragma unroll
                for (int i = 0; i < 4; i++) fma4x4(acc[i], hv[i], w0, w1, w2, w3);
            }
            #pragma unroll
            for (int i = 0; i < 4; i++) {
                int r = ch * 16 + rg * 4 + i;
                if (r < S_) {
                    float4 o;
                    o.x = fmaxf(acc[i].x + bias.x, 0.f);
                    o.y = fmaxf(acc[i].y + bias.y, 0.f);
                    o.z = fmaxf(acc[i].z + bias.z, 0.f);
                    o.w = fmaxf(acc[i].w + bias.w, 0.f);
                    *(float4*)&fs[r * FF_ + c0] = o;
                }
            }
        }
    }
    __syncthreads();

    // ---- 7. FFN2: t2 = f @ W2 + b2 + h2, into h-space ------------------
    {
        const int c0 = (t & 15) * 4, rg = t >> 4;
        float4 acc[3];
        #pragma unroll
        for (int i = 0; i < 3; i++) acc[i] = make_float4(0.f, 0.f, 0.f, 0.f);
        for (int k4 = 0; k4 < FF_; k4 += 4) {
            float4 fv[3];
            #pragma unroll
            for (int i = 0; i < 3; i++) {
                int r = rg + 16 * i;
                fv[i] = (r < S_) ? *(const float4*)&fs[r * FF_ + k4]
                                 : make_float4(0.f, 0.f, 0.f, 0.f);
            }
            float4 w0 = *(const float4*)&W2[(k4 + 0) * 64 + c0];
            float4 w1 = *(const float4*)&W2[(k4 + 1) * 64 + c0];
            float4 w2 = *(const float4*)&W2[(k4 + 2) * 64 + c0];
            float4 w3 = *(const float4*)&W2[(k4 + 3) * 64 + c0];
            #pragma unroll
            for (int i = 0; i < 3; i++) fma4x4(acc[i], fv[i], w0, w1, w2, w3);
        }
        float4 b24 = *(const float4*)&b2[c0];
        #pragma unroll
        for (int i = 0; i < 3; i++) {
            int r = rg + 16 * i;
            if (r < S_) {
                float4 hr = *(const float4*)&h[r * 64 + c0];
                float4 o;
                o.x = acc[i].x + b24.x + hr.x;
                o.y = acc[i].y + b24.y + hr.y;
                o.z = acc[i].z + b24.z + hr.z;
                o.w = acc[i].w + b24.w + hr.w;
                *(float4*)&h[r * 64 + c0] = o;   // t2 overwrites h2 (same owner)
            }
        }
    }
    __syncthreads();

    // ---- 8. LN2: t2 (h-space) -> out (global) --------------------------
    {
        const int wv = t >> 6, d = t & 63;
        const float g = ln2g[d], bb = ln2b[d];
        for (int i = 0; i < 12; i++) {
            int r = wv + 4 * i;
            if (r < S_) {
                float v = h[r * 64 + d];
                float s = v, s2 = v * v;
                #pragma unroll
                for (int off = 32; off; off >>= 1) {
                    s += __shfl_xor(s, off);
                    s2 += __shfl_xor(s2, off);
                }
                float mean = s * (1.0f / 64.0f);
                float var = s2 * (1.0f / 64.0f) - mean * mean;
                float nv = (v - mean) * rsqrtf(var + 1e-5f);
                out[(size_t)b * (S_ * D_) + r * 64 + d] = nv * g + bb;
            }
        }
    }
}

extern "C" void kernel_launch(void* const* d_in, const int* in_sizes, int n_in,
                              void* d_out, int out_size, void* d_ws, size_t ws_size,
                              hipStream_t stream) {
    const float* x    = (const float*)d_in[0];
    const float* Wq   = (const float*)d_in[1];
    const float* bq   = (const float*)d_in[2];
    const float* Wk   = (const float*)d_in[3];
    const float* bk   = (const float*)d_in[4];
    const float* Wv   = (const float*)d_in[5];
    const float* bv   = (const float*)d_in[6];
    const float* Wo   = (const float*)d_in[7];
    const float* bo   = (const float*)d_in[8];
    const float* ln1g = (const float*)d_in[9];
    const float* ln1b = (const float*)d_in[10];
    const float* W1   = (const float*)d_in[11];
    const float* b1   = (const float*)d_in[12];
    const float* W2   = (const float*)d_in[13];
    const float* b2   = (const float*)d_in[14];
    const float* ln2g = (const float*)d_in[15];
    const float* ln2b = (const float*)d_in[16];
    float* out = (float*)d_out;
    float* pe  = (float*)d_ws;

    hipLaunchKernelGGL(pe_kernel, dim3((S_ * D_ + 255) / 256), dim3(256), 0, stream, pe);
    hipLaunchKernelGGL(encoder_kernel, dim3(NB), dim3(256), 0, stream,
                       x, Wq, bq, Wk, bk, Wv, bv, Wo, bo,
                       ln1g, ln1b, W1, b1, W2, b2, ln2g, ln2b, pe, out);
}